// Round 3
// baseline (516.349 us; speedup 1.0000x reference)
//
#include <hip/hip_runtime.h>
#include <hip/hip_bf16.h>
#include <math.h>

#define D 128
#define NND 50000
#define NE 800000
#define NB1 196        // scan blocks: 196*256 = 50176 >= 50000
#define TPITCH 152     // ushort pitch for node transpose tile (304 B = 19*16)

typedef __attribute__((ext_vector_type(8))) short shortx8;
typedef __attribute__((ext_vector_type(4))) float floatx4;

__device__ __forceinline__ float silu_f(float v) {
    // v / (1+e^-v) with hardware rcp (1 ulp) instead of IEEE divide
    return v * __builtin_amdgcn_rcpf(1.0f + __expf(-v));
}
__device__ __forceinline__ unsigned short f2bf(float f) {
    union { float f; unsigned int u; } v; v.f = f;
    unsigned int u = v.u;
    u += 0x7fffu + ((u >> 16) & 1u);   // RNE
    return (unsigned short)(u >> 16);
}
__device__ __forceinline__ void unpk(unsigned int u, float& lo, float& hi) {
    union { unsigned int x; float f; } a, b;
    a.x = u << 16;
    b.x = u & 0xffff0000u;
    lo = a.f; hi = b.f;
}

// ---------------- zero (deg) ----------------
__global__ void zero_kernel(float4* __restrict__ p, int n4) {
    int i = blockIdx.x * blockDim.x + threadIdx.x;
    float4 z = make_float4(0.f, 0.f, 0.f, 0.f);
    for (; i < n4; i += gridDim.x * blockDim.x) p[i] = z;
}

// ---------------- CSR build ----------------
__global__ void hist_kernel(const int* __restrict__ ei, int* __restrict__ deg) {
    int e = blockIdx.x * 256 + threadIdx.x;     // NE = 3125*256 exactly
    atomicAdd(&deg[ei[e]], 1);
}

__global__ void scan1_kernel(const int* __restrict__ deg,
                             int* __restrict__ part, int* __restrict__ bsum) {
    __shared__ int s[256];
    const int tid = threadIdx.x;
    const int i = blockIdx.x * 256 + tid;
    int v = (i < NND) ? deg[i] : 0;
    s[tid] = v;
    __syncthreads();
    #pragma unroll
    for (int off = 1; off < 256; off <<= 1) {
        int t = (tid >= off) ? s[tid - off] : 0;
        __syncthreads();
        s[tid] += t;
        __syncthreads();
    }
    part[i] = s[tid] - v;                        // exclusive
    if (tid == 255) bsum[blockIdx.x] = s[255];
}

__global__ void scan2_kernel(const int* __restrict__ bsum, int* __restrict__ boff) {
    __shared__ int s[256];
    const int tid = threadIdx.x;
    int v = (tid < NB1) ? bsum[tid] : 0;
    s[tid] = v;
    __syncthreads();
    #pragma unroll
    for (int off = 1; off < 256; off <<= 1) {
        int t = (tid >= off) ? s[tid - off] : 0;
        __syncthreads();
        s[tid] += t;
        __syncthreads();
    }
    if (tid < NB1) boff[tid] = s[tid] - v;       // exclusive
}

__global__ void scan3_kernel(const int* __restrict__ part, const int* __restrict__ boff,
                             int* __restrict__ rowptr, int* __restrict__ cursor) {
    int i = blockIdx.x * 256 + threadIdx.x;
    if (i < NND) {
        int v = part[i] + boff[i >> 8];
        rowptr[i] = v;
        cursor[i] = v;
    } else if (i == NND) {
        rowptr[NND] = NE;
    }
}

// scatter row + col + dist2 into CSR order
__global__ void scatter_kernel(const int* __restrict__ ei, const float* __restrict__ pos,
                               int* __restrict__ cursor,
                               int* __restrict__ ecol, int* __restrict__ erow,
                               float* __restrict__ ed2) {
    int e = blockIdx.x * 256 + threadIdx.x;     // NE exact multiple of 256
    int r = ei[e], c = ei[NE + e];
    float dx = pos[r * 3 + 0] - pos[c * 3 + 0];
    float dy = pos[r * 3 + 1] - pos[c * 3 + 1];
    float dz = pos[r * 3 + 2] - pos[c * 3 + 2];
    int slot = atomicAdd(&cursor[r], 1);
    ecol[slot] = c;
    erow[slot] = r;
    ed2[slot] = dx * dx + dy * dy + dz * dz;
}

// ---------------- fused weight swizzle (all 4 matrices + wlf, 1 launch) ----
// Wf flat f = (((ks*4+quad)*128)+n*16+mrow)*8+j  <->  W[k=ks*32+quad*8+j][col=n*16+mrow]
__global__ void wswzall_kernel(const float* __restrict__ W1e, const float* __restrict__ W1n,
                               const float* __restrict__ W2e, const float* __restrict__ W2n,
                               unsigned short* __restrict__ w1f, unsigned short* __restrict__ w1nf,
                               unsigned short* __restrict__ w2f, unsigned short* __restrict__ w2nf,
                               unsigned short* __restrict__ wlf) {
    const int b = blockIdx.x;
    const float* W; unsigned short* Wf; int lb;
    if (b < 128)      { W = W1e; Wf = w1f;  lb = b; }
    else if (b < 256) { W = W1n; Wf = w1nf; lb = b - 128; }
    else if (b < 320) { W = W2e; Wf = w2f;  lb = b - 256; }
    else if (b < 384) { W = W2n; Wf = w2nf; lb = b - 320; }
    else {
        if (threadIdx.x < 128) wlf[threadIdx.x] = f2bf(W1e[256 * D + threadIdx.x]);
        return;
    }
    int f = lb * 256 + threadIdx.x;
    int j    = f & 7;
    int mrow = (f >> 3) & 15;
    int n    = (f >> 7) & 7;
    int rest = f >> 10;
    int quad = rest & 3;
    int ks   = rest >> 2;
    int col = n * 16 + mrow;
    int k   = ks * 32 + quad * 8 + j;
    Wf[f] = f2bf(W[k * D + col]);
}

// ---------------- x -> bf16 ----------------
__global__ void x2bf_kernel(const float4* __restrict__ x4, uint2* __restrict__ xbf) {
    int i = blockIdx.x * 256 + threadIdx.x;   // NND*D/4 = 1.6M exact
    float4 v = x4[i];
    uint2 o;
    o.x = (unsigned int)f2bf(v.x) | ((unsigned int)f2bf(v.y) << 16);
    o.y = (unsigned int)f2bf(v.z) | ((unsigned int)f2bf(v.w) << 16);
    xbf[i] = o;
}

// ---------------- A' = bf16(x@W1e_top + b1e), B = bf16(x@W1e_bot)  [MFMA] ----
__global__ __launch_bounds__(256) void precompute_kernel(
        const unsigned short* __restrict__ xbf,
        const unsigned short* __restrict__ w1f,   // 256x128 swizzled
        const float* __restrict__ b1e,
        unsigned short* __restrict__ A,
        unsigned short* __restrict__ Bm) {
    const int t    = threadIdx.x;
    const int wv   = t >> 6;
    const int lane = t & 63;
    const int mrow = lane & 15;
    const int quad = lane >> 4;
    const int tile = blockIdx.x * 4 + wv;
    if (tile >= 3125) return;
    const int n0 = tile * 16;

    const uint4* xrow = (const uint4*)(xbf + ((size_t)(n0 + mrow) << 7));
    const uint4* wp   = (const uint4*)w1f;

    floatx4 accA[8], accB[8];
    #pragma unroll
    for (int n = 0; n < 8; ++n) {
        accA[n] = (floatx4){0.f, 0.f, 0.f, 0.f};
        accB[n] = (floatx4){0.f, 0.f, 0.f, 0.f};
    }

    #pragma unroll
    for (int s = 0; s < 4; ++s) {
        union { uint4 u; shortx8 v; } af;
        af.u = xrow[s * 4 + quad];
        const int baseA = (s * 4 + quad) * 128 + mrow;
        const int baseB = ((s + 4) * 4 + quad) * 128 + mrow;
        #pragma unroll
        for (int n = 0; n < 8; ++n) {
            union { uint4 u; shortx8 v; } bfA, bfB;
            bfA.u = wp[baseA + n * 16];
            bfB.u = wp[baseB + n * 16];
            accA[n] = __builtin_amdgcn_mfma_f32_16x16x32_bf16(af.v, bfA.v, accA[n], 0, 0, 0);
            accB[n] = __builtin_amdgcn_mfma_f32_16x16x32_bf16(af.v, bfB.v, accB[n], 0, 0, 0);
        }
    }

    float bb[8];
    #pragma unroll
    for (int n = 0; n < 8; ++n) bb[n] = b1e[n * 16 + mrow];

    #pragma unroll
    for (int reg = 0; reg < 4; ++reg) {
        const int node = n0 + quad * 4 + reg;
        #pragma unroll
        for (int n = 0; n < 8; ++n) {
            const int col = n * 16 + mrow;
            A[(size_t)node * D + col]  = f2bf(accA[n][reg] + bb[n]);
            Bm[(size_t)node * D + col] = f2bf(accB[n][reg]);
        }
    }
}

// ---------------- E1: uniform edge MLP (wave = 16 CSR-consecutive edges) ----
// No loops, no masking: 800000/16 = 50000 full tiles. Writes ef with
// per-row column permutation p = mrow*8 + n (holds logical col k = n*16+mrow)
// so each lane emits 4 fully-coalesced 16B stores straight from the C-layout.
__global__ __launch_bounds__(256) void edgemlp_kernel(
        const unsigned short* __restrict__ Abf,
        const unsigned short* __restrict__ Bbf,
        const int* __restrict__ erow,
        const int* __restrict__ ecol,
        const float* __restrict__ ed2,
        const unsigned short* __restrict__ wlf,
        const unsigned short* __restrict__ W2f,
        const float* __restrict__ b2e,
        unsigned short* __restrict__ ef) {
    const int t    = threadIdx.x;
    const int wv   = t >> 6;
    const int lane = t & 63;
    const int mrow = lane & 15;
    const int quad = lane >> 4;
    const int tile = blockIdx.x * 4 + wv;       // 12500 * 4 = 50000 exact
    const int e0   = tile * 16;
    const int eme  = e0 + mrow;                 // this lane's A-frag edge

    const int   r  = erow[eme];                 // CSR-sorted -> L1 broadcast
    const int   c  = ecol[eme];
    const float d2 = ed2[eme];

    const uint4* arow = (const uint4*)(Abf + ((size_t)r << 7));
    const uint4* brow = (const uint4*)(Bbf + ((size_t)c << 7));
    const uint4* wlq  = (const uint4*)wlf;
    const uint4* w2p  = (const uint4*)W2f;

    floatx4 acc[8];
    #pragma unroll
    for (int k = 0; k < 8; ++k) acc[k] = (floatx4){0.f, 0.f, 0.f, 0.f};

    #pragma unroll
    for (int s = 0; s < 4; ++s) {
        uint4 au = arow[s * 4 + quad];
        uint4 bu = brow[s * 4 + quad];
        uint4 wu = wlq[s * 4 + quad];

        float a0, a1, a2, a3, a4, a5, a6, a7;
        float q0, q1, q2, q3, q4, q5, q6, q7;
        float w0, w1, w2, w3, w4, w5, w6, w7;
        unpk(au.x, a0, a1); unpk(au.y, a2, a3);
        unpk(au.z, a4, a5); unpk(au.w, a6, a7);
        unpk(bu.x, q0, q1); unpk(bu.y, q2, q3);
        unpk(bu.z, q4, q5); unpk(bu.w, q6, q7);
        unpk(wu.x, w0, w1); unpk(wu.y, w2, w3);
        unpk(wu.z, w4, w5); unpk(wu.w, w6, w7);

        float h0 = silu_f(fmaf(d2, w0, a0 + q0));
        float h1 = silu_f(fmaf(d2, w1, a1 + q1));
        float h2 = silu_f(fmaf(d2, w2, a2 + q2));
        float h3 = silu_f(fmaf(d2, w3, a3 + q3));
        float h4 = silu_f(fmaf(d2, w4, a4 + q4));
        float h5 = silu_f(fmaf(d2, w5, a5 + q5));
        float h6 = silu_f(fmaf(d2, w6, a6 + q6));
        float h7 = silu_f(fmaf(d2, w7, a7 + q7));

        union { shortx8 v; __hip_bfloat162 p[4]; } af;
        af.p[0] = __float22bfloat162_rn(float2{h0, h1});
        af.p[1] = __float22bfloat162_rn(float2{h2, h3});
        af.p[2] = __float22bfloat162_rn(float2{h4, h5});
        af.p[3] = __float22bfloat162_rn(float2{h6, h7});

        const int base = (s * 4 + quad) * 128 + mrow;
        #pragma unroll
        for (int k = 0; k < 8; ++k) {
            union { uint4 u; shortx8 v; } bf;
            bf.u = w2p[base + k * 16];
            acc[k] = __builtin_amdgcn_mfma_f32_16x16x32_bf16(af.v, bf.v, acc[k], 0, 0, 0);
        }
    }

    float bias[8];
    #pragma unroll
    for (int k = 0; k < 8; ++k) bias[k] = b2e[k * 16 + mrow];

    #pragma unroll
    for (int reg = 0; reg < 4; ++reg) {
        const int edge = e0 + quad * 4 + reg;   // C-layout row = edge-in-tile
        union { uint4 u; __hip_bfloat162 p[4]; } ov;
        #pragma unroll
        for (int n = 0; n < 4; ++n) {
            float v0 = silu_f(acc[2 * n + 0][reg] + bias[2 * n + 0]);
            float v1 = silu_f(acc[2 * n + 1][reg] + bias[2 * n + 1]);
            ov.p[n] = __float22bfloat162_rn(float2{v0, v1});
        }
        *(uint4*)(ef + (((size_t)edge) << 7) + mrow * 8) = ov.u;
    }
}

// ---------------- E2: segmented sum over CSR ef rows (wave = node) ----------
// 16B/lane loads: one wave-load covers 4 rows (1024B contiguous). Sums
// reduced across the 4 sub-groups; lanes 0-15 write the canonical f32 row.
__global__ __launch_bounds__(256) void aggsum_kernel(
        const unsigned short* __restrict__ ef,
        const int* __restrict__ rowptr,
        float* __restrict__ aggf) {
    const int t    = threadIdx.x;
    const int lane = t & 63;
    const int node = blockIdx.x * 4 + (t >> 6);  // 12500 * 4 = 50000 exact
    const int start = rowptr[node];
    const int end   = rowptr[node + 1];
    const int sub  = lane >> 4;                  // row within 4-row block
    const int j    = lane & 15;                  // 16B chunk within row

    const uint4* ef4 = (const uint4*)ef;         // row = 16 uint4

    float s[8];
    #pragma unroll
    for (int i = 0; i < 8; ++i) s[i] = 0.f;

    for (int e = start; e < end; e += 4) {
        const int  er    = e + sub;
        const bool valid = er < end;
        const int  safe  = valid ? er : start;
        uint4 u = ef4[(size_t)safe * 16 + j];
        float f0, f1, f2, f3, f4, f5, f6, f7;
        unpk(u.x, f0, f1); unpk(u.y, f2, f3);
        unpk(u.z, f4, f5); unpk(u.w, f6, f7);
        if (valid) {
            s[0] += f0; s[1] += f1; s[2] += f2; s[3] += f3;
            s[4] += f4; s[5] += f5; s[6] += f6; s[7] += f7;
        }
    }
    #pragma unroll
    for (int i = 0; i < 8; ++i) {
        s[i] += __shfl_xor(s[i], 16);
        s[i] += __shfl_xor(s[i], 32);
    }
    if (sub == 0) {
        // permuted position p = j*8 + i  ->  canonical col k = i*16 + j
        float* dst = aggf + ((size_t)node << 7) + j;
        #pragma unroll
        for (int i = 0; i < 8; ++i) dst[i * 16] = s[i];
    }
}

// ---------------- fallback: fused edge MLP + aggregation (f32 agg out) -----
__global__ __launch_bounds__(256, 2) void edgeagg_kernel(
        const unsigned short* __restrict__ Abf,
        const unsigned short* __restrict__ Bbf,
        const int* __restrict__ rowptr,
        const int* __restrict__ ecol,
        const float* __restrict__ ed2,
        const unsigned short* __restrict__ wlf,
        const unsigned short* __restrict__ W2f,
        const float* __restrict__ b2e,
        float* __restrict__ aggf) {
    const int t    = threadIdx.x;
    const int wv   = t >> 6;
    const int lane = t & 63;
    const int mrow = lane & 15;
    const int quad = lane >> 4;
    const int node = blockIdx.x * 4 + wv;        // 12500 * 4 = 50000 exact

    const int start = rowptr[node];
    const int d     = rowptr[node + 1] - start;

    const uint4* arow = (const uint4*)(Abf + ((size_t)node << 7));
    const uint4* wlq  = (const uint4*)wlf;
    uint4 au[4], wlu[4];
    #pragma unroll
    for (int s = 0; s < 4; ++s) {
        au[s]  = arow[s * 4 + quad];
        wlu[s] = wlq[s * 4 + quad];
    }
    float bias[8];
    #pragma unroll
    for (int k = 0; k < 8; ++k) bias[k] = b2e[k * 16 + mrow];

    float nacc[8];
    #pragma unroll
    for (int k = 0; k < 8; ++k) nacc[k] = 0.f;

    const uint4* w2p = (const uint4*)W2f;

    for (int tb = 0; tb < d; tb += 16) {
        const int  ei16 = tb + mrow;
        const bool ve   = ei16 < d;
        const int  idx  = start + (ve ? ei16 : 0);
        const int  c    = ecol[idx];
        float d2        = ed2[idx];
        d2 = ve ? d2 : 0.f;
        const uint4* brow = (const uint4*)(Bbf + ((size_t)c << 7));

        floatx4 acc[8];
        #pragma unroll
        for (int k = 0; k < 8; ++k) acc[k] = (floatx4){0.f, 0.f, 0.f, 0.f};

        #pragma unroll
        for (int s = 0; s < 4; ++s) {
            uint4 bu = brow[s * 4 + quad];

            float a0, a1, a2, a3, a4, a5, a6, a7;
            float q0, q1, q2, q3, q4, q5, q6, q7;
            float w0, w1, w2, w3, w4, w5, w6, w7;
            unpk(au[s].x, a0, a1); unpk(au[s].y, a2, a3);
            unpk(au[s].z, a4, a5); unpk(au[s].w, a6, a7);
            unpk(bu.x, q0, q1); unpk(bu.y, q2, q3);
            unpk(bu.z, q4, q5); unpk(bu.w, q6, q7);
            unpk(wlu[s].x, w0, w1); unpk(wlu[s].y, w2, w3);
            unpk(wlu[s].z, w4, w5); unpk(wlu[s].w, w6, w7);

            float h0 = silu_f(fmaf(d2, w0, a0 + q0));
            float h1 = silu_f(fmaf(d2, w1, a1 + q1));
            float h2 = silu_f(fmaf(d2, w2, a2 + q2));
            float h3 = silu_f(fmaf(d2, w3, a3 + q3));
            float h4 = silu_f(fmaf(d2, w4, a4 + q4));
            float h5 = silu_f(fmaf(d2, w5, a5 + q5));
            float h6 = silu_f(fmaf(d2, w6, a6 + q6));
            float h7 = silu_f(fmaf(d2, w7, a7 + q7));

            union { shortx8 v; __hip_bfloat162 p[4]; } af;
            af.p[0] = __float22bfloat162_rn(float2{h0, h1});
            af.p[1] = __float22bfloat162_rn(float2{h2, h3});
            af.p[2] = __float22bfloat162_rn(float2{h4, h5});
            af.p[3] = __float22bfloat162_rn(float2{h6, h7});

            const int base = (s * 4 + quad) * 128 + mrow;
            #pragma unroll
            for (int k = 0; k < 8; ++k) {
                union { uint4 u; shortx8 v; } bf;
                bf.u = w2p[base + k * 16];
                acc[k] = __builtin_amdgcn_mfma_f32_16x16x32_bf16(af.v, bf.v, acc[k], 0, 0, 0);
            }
        }

        #pragma unroll
        for (int reg = 0; reg < 4; ++reg) {
            const bool vr = (tb + quad * 4 + reg) < d;
            #pragma unroll
            for (int k = 0; k < 8; ++k)
                nacc[k] += vr ? silu_f(acc[k][reg] + bias[k]) : 0.f;
        }
    }

    #pragma unroll
    for (int k = 0; k < 8; ++k) {
        float v = nacc[k];
        v += __shfl_xor(v, 16);
        v += __shfl_xor(v, 32);
        nacc[k] = v;
    }
    const int n8a = quad * 2, n8b = quad * 2 + 1;
    aggf[(size_t)node * D + n8a * 16 + mrow] = nacc[n8a];
    aggf[(size_t)node * D + n8b * 16 + mrow] = nacc[n8b];
}

// ---------------- node MLP + residual + LayerNorm  [MFMA] ----------------
// 1 wave per block, block = 16 nodes. Stage1 K=256 ([x|agg] bf16), transpose
// via LDS (304 B pitch), stage2 K=128, epilogue residual + LN via quad shfl.
// agg arrives as f32; packed to bf16 frags on load.
__global__ __launch_bounds__(64) void node_kernel(
        const unsigned short* __restrict__ xbf,
        const float* __restrict__ aggf,
        const unsigned short* __restrict__ w1nf,  // 256x128 swizzled
        const float* __restrict__ b1n,
        const unsigned short* __restrict__ w2nf,  // 128x128 swizzled
        const float* __restrict__ b2n,
        const float* __restrict__ x,
        const float* __restrict__ gamma,
        const float* __restrict__ beta,
        float* __restrict__ out) {
    __shared__ __align__(16) unsigned short ts[16 * TPITCH];
    const int lane = threadIdx.x;
    const int mrow = lane & 15;
    const int quad = lane >> 4;
    const int n0 = blockIdx.x * 16;      // 3125 blocks exact

    const uint4*  xrow  = (const uint4*)(xbf + ((size_t)(n0 + mrow) << 7));
    const float4* growf = (const float4*)(aggf + ((size_t)(n0 + mrow) << 7));
    const uint4*  w1p   = (const uint4*)w1nf;
    const uint4*  w2p   = (const uint4*)w2nf;

    floatx4 acc[8];
    #pragma unroll
    for (int n = 0; n < 8; ++n) {
        float b = b1n[n * 16 + mrow];
        acc[n] = (floatx4){b, b, b, b};
    }

    #pragma unroll
    for (int s = 0; s < 4; ++s) {
        union { uint4 u; shortx8 v; } af;
        af.u = xrow[s * 4 + quad];
        const int base = (s * 4 + quad) * 128 + mrow;
        #pragma unroll
        for (int n = 0; n < 8; ++n) {
            union { uint4 u; shortx8 v; } bf;
            bf.u = w1p[base + n * 16];
            acc[n] = __builtin_amdgcn_mfma_f32_16x16x32_bf16(af.v, bf.v, acc[n], 0, 0, 0);
        }
    }
    #pragma unroll
    for (int s = 0; s < 4; ++s) {
        float4 g0 = growf[(s * 4 + quad) * 2 + 0];
        float4 g1 = growf[(s * 4 + quad) * 2 + 1];
        union { shortx8 v; __hip_bfloat162 p[4]; } af;
        af.p[0] = __float22bfloat162_rn(float2{g0.x, g0.y});
        af.p[1] = __float22bfloat162_rn(float2{g0.z, g0.w});
        af.p[2] = __float22bfloat162_rn(float2{g1.x, g1.y});
        af.p[3] = __float22bfloat162_rn(float2{g1.z, g1.w});
        const int base = ((s + 4) * 4 + quad) * 128 + mrow;
        #pragma unroll
        for (int n = 0; n < 8; ++n) {
            union { uint4 u; shortx8 v; } bf;
            bf.u = w1p[base + n * 16];
            acc[n] = __builtin_amdgcn_mfma_f32_16x16x32_bf16(af.v, bf.v, acc[n], 0, 0, 0);
        }
    }

    // silu -> LDS (row-major [m][col], transpose for stage-2 A-frags)
    #pragma unroll
    for (int reg = 0; reg < 4; ++reg) {
        const int m = quad * 4 + reg;
        #pragma unroll
        for (int n = 0; n < 8; ++n)
            ts[m * TPITCH + n * 16 + mrow] = f2bf(silu_f(acc[n][reg]));
    }
    __syncthreads();   // single wave: cheap; guarantees LDS RAW ordering

    floatx4 acc2[8];
    #pragma unroll
    for (int n = 0; n < 8; ++n) {
        float b = b2n[n * 16 + mrow];
        acc2[n] = (floatx4){b, b, b, b};
    }
    #pragma unroll
    for (int s = 0; s < 4; ++s) {
        shortx8 af2 = *(const shortx8*)((const char*)ts +
                        mrow * (TPITCH * 2) + (s * 4 + quad) * 16);
        const int base = (s * 4 + quad) * 128 + mrow;
        #pragma unroll
        for (int n = 0; n < 8; ++n) {
            union { uint4 u; shortx8 v; } bf;
            bf.u = w2p[base + n * 16];
            acc2[n] = __builtin_amdgcn_mfma_f32_16x16x32_bf16(af2, bf.v, acc2[n], 0, 0, 0);
        }
    }

    // epilogue: residual + LayerNorm (reduce over the 16 lanes of each quad)
    float g[8], bt[8];
    #pragma unroll
    for (int n = 0; n < 8; ++n) {
        g[n]  = gamma[n * 16 + mrow];
        bt[n] = beta[n * 16 + mrow];
    }
    #pragma unroll
    for (int reg = 0; reg < 4; ++reg) {
        const int node = n0 + quad * 4 + reg;
        float u[8];
        float s1 = 0.f, s2 = 0.f;
        #pragma unroll
        for (int n = 0; n < 8; ++n) {
            u[n] = acc2[n][reg] + x[(size_t)node * D + n * 16 + mrow];
            s1 += u[n];
            s2 += u[n] * u[n];
        }
        #pragma unroll
        for (int off = 1; off < 16; off <<= 1) {
            s1 += __shfl_xor(s1, off);
            s2 += __shfl_xor(s2, off);
        }
        const float mu  = s1 * (1.f / 128.f);
        const float var = s2 * (1.f / 128.f) - mu * mu;
        const float rs  = rsqrtf(var + 1e-5f);
        #pragma unroll
        for (int n = 0; n < 8; ++n)
            out[(size_t)node * D + n * 16 + mrow] = (u[n] - mu) * rs * g[n] + bt[n];
    }
}

extern "C" void kernel_launch(void* const* d_in, const int* in_sizes, int n_in,
                              void* d_out, int out_size, void* d_ws, size_t ws_size,
                              hipStream_t stream) {
    const float* x     = (const float*)d_in[0];
    const float* pos   = (const float*)d_in[1];
    const int*   ei    = (const int*)d_in[2];
    const float* W1e   = (const float*)d_in[3];
    const float* b1e   = (const float*)d_in[4];
    const float* W2e   = (const float*)d_in[5];
    const float* b2e   = (const float*)d_in[6];
    const float* W1n   = (const float*)d_in[7];
    const float* b1n   = (const float*)d_in[8];
    const float* W2n   = (const float*)d_in[9];
    const float* b2n   = (const float*)d_in[10];
    const float* gamma = (const float*)d_in[11];
    const float* beta  = (const float*)d_in[12];
    float* out = (float*)d_out;

    // ws layout (all offsets 16B-aligned)
    float*          aggf   = (float*)d_ws;                            // 25.6 MB (f32 agg)
    int*            deg    = (int*)(aggf + (size_t)NND * D);          // 50176
    int*            part   = deg + 50176;
    int*            bsum   = part + 50176;
    int*            boff   = bsum + 256;
    int*            rowptr = boff + 256;                              // 50004
    int*            cursor = rowptr + 50004;                          // 50000
    int*            ecol   = cursor + 50000;                          // 800000
    int*            erow   = ecol + NE;                               // 800000
    float*          ed2    = (float*)(erow + NE);                     // 800000
    unsigned short* Abf    = (unsigned short*)(ed2 + NE);             // 12.8 MB
    unsigned short* Bbf    = Abf + (size_t)NND * D;                   // 12.8 MB
    unsigned short* xbf    = Bbf + (size_t)NND * D;                   // 12.8 MB
    unsigned short* w1f    = xbf + (size_t)NND * D;                   // 64 KB (256x128)
    unsigned short* w1nf   = w1f + 256 * D;                           // 64 KB (256x128)
    unsigned short* w2f    = w1nf + 256 * D;                          // 32 KB (128x128)
    unsigned short* w2nf   = w2f + D * D;                             // 32 KB (128x128)
    unsigned short* wlf    = w2nf + D * D;                            // 256 B
    unsigned short* ef     = wlf + 128;                               // 204.8 MB (bf16 edge feats)

    const size_t need_big = (size_t)((char*)(ef + (size_t)NE * D) - (char*)d_ws);
    const bool bigws = ws_size >= need_big;

    // zero deg only (aggf fully overwritten by aggsum/edgeagg; ef by edgemlp)
    zero_kernel<<<49, 256, 0, stream>>>((float4*)deg, 50176 / 4);

    // CSR build
    hist_kernel<<<NE / 256, 256, 0, stream>>>(ei, deg);
    scan1_kernel<<<NB1, 256, 0, stream>>>(deg, part, bsum);
    scan2_kernel<<<1, 256, 0, stream>>>(bsum, boff);
    scan3_kernel<<<197, 256, 0, stream>>>(part, boff, rowptr, cursor);
    scatter_kernel<<<NE / 256, 256, 0, stream>>>(ei, pos, cursor, ecol, erow, ed2);

    // fused weight swizzles (1 launch) + x conversion
    wswzall_kernel<<<385, 256, 0, stream>>>(W1e, W1n, W2e, W2n,
                                            w1f, w1nf, w2f, w2nf, wlf);
    x2bf_kernel<<<(NND * D / 4) / 256, 256, 0, stream>>>((const float4*)x, (uint2*)xbf);

    // A'/B precompute (MFMA)
    precompute_kernel<<<782, 256, 0, stream>>>(xbf, w1f, b1e, Abf, Bbf);

    if (bigws) {
        // E1: uniform edge MLP -> ef (CSR order, col-permuted rows)
        edgemlp_kernel<<<NE / 16 / 4, 256, 0, stream>>>(Abf, Bbf, erow, ecol, ed2,
                                                        wlf, w2f, b2e, ef);
        // E2: segmented sum -> aggf (canonical f32 layout)
        aggsum_kernel<<<NND / 4, 256, 0, stream>>>(ef, rowptr, aggf);
    } else {
        // fallback: fused per-node path (workspace too small for ef)
        edgeagg_kernel<<<NND / 4, 256, 0, stream>>>(Abf, Bbf, rowptr, ecol, ed2,
                                                    wlf, w2f, b2e, aggf);
    }

    // node MLP + residual + LN (MFMA)
    node_kernel<<<NND / 16, 64, 0, stream>>>(xbf, aggf, w1nf, b1n, w2nf, b2n,
                                             x, gamma, beta, out);
}

// Round 4
// 415.579 us; speedup vs baseline: 1.2425x; 1.2425x over previous
//
#include <hip/hip_runtime.h>
#include <hip/hip_bf16.h>
#include <math.h>

#define D 128
#define NND 50000
#define NE 800000
#define NB1 196        // scan blocks: 196*256 = 50176 >= 50000
#define TPITCH 152     // ushort pitch for node transpose tile (304 B = 19*16)

typedef __attribute__((ext_vector_type(8))) short shortx8;
typedef __attribute__((ext_vector_type(4))) float floatx4;

__device__ __forceinline__ float silu_f(float v) {
    // v / (1+e^-v) with hardware rcp (1 ulp) instead of IEEE divide
    return v * __builtin_amdgcn_rcpf(1.0f + __expf(-v));
}
__device__ __forceinline__ unsigned short f2bf(float f) {
    union { float f; unsigned int u; } v; v.f = f;
    unsigned int u = v.u;
    u += 0x7fffu + ((u >> 16) & 1u);   // RNE
    return (unsigned short)(u >> 16);
}
__device__ __forceinline__ void unpk(unsigned int u, float& lo, float& hi) {
    union { unsigned int x; float f; } a, b;
    a.x = u << 16;
    b.x = u & 0xffff0000u;
    lo = a.f; hi = b.f;
}

// ---------------- zero (deg) ----------------
__global__ void zero_kernel(float4* __restrict__ p, int n4) {
    int i = blockIdx.x * blockDim.x + threadIdx.x;
    float4 z = make_float4(0.f, 0.f, 0.f, 0.f);
    for (; i < n4; i += gridDim.x * blockDim.x) p[i] = z;
}

// ---------------- CSR build ----------------
__global__ void hist_kernel(const int* __restrict__ ei, int* __restrict__ deg) {
    int e = blockIdx.x * 256 + threadIdx.x;     // NE = 3125*256 exactly
    atomicAdd(&deg[ei[e]], 1);
}

__global__ void scan1_kernel(const int* __restrict__ deg,
                             int* __restrict__ part, int* __restrict__ bsum) {
    __shared__ int s[256];
    const int tid = threadIdx.x;
    const int i = blockIdx.x * 256 + tid;
    int v = (i < NND) ? deg[i] : 0;
    s[tid] = v;
    __syncthreads();
    #pragma unroll
    for (int off = 1; off < 256; off <<= 1) {
        int t = (tid >= off) ? s[tid - off] : 0;
        __syncthreads();
        s[tid] += t;
        __syncthreads();
    }
    part[i] = s[tid] - v;                        // exclusive
    if (tid == 255) bsum[blockIdx.x] = s[255];
}

__global__ void scan2_kernel(const int* __restrict__ bsum, int* __restrict__ boff) {
    __shared__ int s[256];
    const int tid = threadIdx.x;
    int v = (tid < NB1) ? bsum[tid] : 0;
    s[tid] = v;
    __syncthreads();
    #pragma unroll
    for (int off = 1; off < 256; off <<= 1) {
        int t = (tid >= off) ? s[tid - off] : 0;
        __syncthreads();
        s[tid] += t;
        __syncthreads();
    }
    if (tid < NB1) boff[tid] = s[tid] - v;       // exclusive
}

__global__ void scan3_kernel(const int* __restrict__ part, const int* __restrict__ boff,
                             int* __restrict__ rowptr, int* __restrict__ cursor) {
    int i = blockIdx.x * 256 + threadIdx.x;
    if (i < NND) {
        int v = part[i] + boff[i >> 8];
        rowptr[i] = v;
        cursor[i] = v;
    } else if (i == NND) {
        rowptr[NND] = NE;
    }
}

// scatter row + col + dist2 into CSR order
__global__ void scatter_kernel(const int* __restrict__ ei, const float* __restrict__ pos,
                               int* __restrict__ cursor,
                               int* __restrict__ ecol, int* __restrict__ erow,
                               float* __restrict__ ed2) {
    int e = blockIdx.x * 256 + threadIdx.x;     // NE exact multiple of 256
    int r = ei[e], c = ei[NE + e];
    float dx = pos[r * 3 + 0] - pos[c * 3 + 0];
    float dy = pos[r * 3 + 1] - pos[c * 3 + 1];
    float dz = pos[r * 3 + 2] - pos[c * 3 + 2];
    int slot = atomicAdd(&cursor[r], 1);
    ecol[slot] = c;
    erow[slot] = r;
    ed2[slot] = dx * dx + dy * dy + dz * dz;
}

// ---------------- fused weight swizzle (all 4 matrices + wlf, 1 launch) ----
// Wf flat f = (((ks*4+quad)*128)+n*16+mrow)*8+j  <->  W[k=ks*32+quad*8+j][col=n*16+mrow]
__global__ void wswzall_kernel(const float* __restrict__ W1e, const float* __restrict__ W1n,
                               const float* __restrict__ W2e, const float* __restrict__ W2n,
                               unsigned short* __restrict__ w1f, unsigned short* __restrict__ w1nf,
                               unsigned short* __restrict__ w2f, unsigned short* __restrict__ w2nf,
                               unsigned short* __restrict__ wlf) {
    const int b = blockIdx.x;
    const float* W; unsigned short* Wf; int lb;
    if (b < 128)      { W = W1e; Wf = w1f;  lb = b; }
    else if (b < 256) { W = W1n; Wf = w1nf; lb = b - 128; }
    else if (b < 320) { W = W2e; Wf = w2f;  lb = b - 256; }
    else if (b < 384) { W = W2n; Wf = w2nf; lb = b - 320; }
    else {
        if (threadIdx.x < 128) wlf[threadIdx.x] = f2bf(W1e[256 * D + threadIdx.x]);
        return;
    }
    int f = lb * 256 + threadIdx.x;
    int j    = f & 7;
    int mrow = (f >> 3) & 15;
    int n    = (f >> 7) & 7;
    int rest = f >> 10;
    int quad = rest & 3;
    int ks   = rest >> 2;
    int col = n * 16 + mrow;
    int k   = ks * 32 + quad * 8 + j;
    Wf[f] = f2bf(W[k * D + col]);
}

// ---------------- x -> bf16 ----------------
__global__ void x2bf_kernel(const float4* __restrict__ x4, uint2* __restrict__ xbf) {
    int i = blockIdx.x * 256 + threadIdx.x;   // NND*D/4 = 1.6M exact
    float4 v = x4[i];
    uint2 o;
    o.x = (unsigned int)f2bf(v.x) | ((unsigned int)f2bf(v.y) << 16);
    o.y = (unsigned int)f2bf(v.z) | ((unsigned int)f2bf(v.w) << 16);
    xbf[i] = o;
}

// ---------------- A' = bf16(x@W1e_top + b1e), B = bf16(x@W1e_bot)  [MFMA] ----
__global__ __launch_bounds__(256) void precompute_kernel(
        const unsigned short* __restrict__ xbf,
        const unsigned short* __restrict__ w1f,   // 256x128 swizzled
        const float* __restrict__ b1e,
        unsigned short* __restrict__ A,
        unsigned short* __restrict__ Bm) {
    const int t    = threadIdx.x;
    const int wv   = t >> 6;
    const int lane = t & 63;
    const int mrow = lane & 15;
    const int quad = lane >> 4;
    const int tile = blockIdx.x * 4 + wv;
    if (tile >= 3125) return;
    const int n0 = tile * 16;

    const uint4* xrow = (const uint4*)(xbf + ((size_t)(n0 + mrow) << 7));
    const uint4* wp   = (const uint4*)w1f;

    floatx4 accA[8], accB[8];
    #pragma unroll
    for (int n = 0; n < 8; ++n) {
        accA[n] = (floatx4){0.f, 0.f, 0.f, 0.f};
        accB[n] = (floatx4){0.f, 0.f, 0.f, 0.f};
    }

    #pragma unroll
    for (int s = 0; s < 4; ++s) {
        union { uint4 u; shortx8 v; } af;
        af.u = xrow[s * 4 + quad];
        const int baseA = (s * 4 + quad) * 128 + mrow;
        const int baseB = ((s + 4) * 4 + quad) * 128 + mrow;
        #pragma unroll
        for (int n = 0; n < 8; ++n) {
            union { uint4 u; shortx8 v; } bfA, bfB;
            bfA.u = wp[baseA + n * 16];
            bfB.u = wp[baseB + n * 16];
            accA[n] = __builtin_amdgcn_mfma_f32_16x16x32_bf16(af.v, bfA.v, accA[n], 0, 0, 0);
            accB[n] = __builtin_amdgcn_mfma_f32_16x16x32_bf16(af.v, bfB.v, accB[n], 0, 0, 0);
        }
    }

    float bb[8];
    #pragma unroll
    for (int n = 0; n < 8; ++n) bb[n] = b1e[n * 16 + mrow];

    #pragma unroll
    for (int reg = 0; reg < 4; ++reg) {
        const int node = n0 + quad * 4 + reg;
        #pragma unroll
        for (int n = 0; n < 8; ++n) {
            const int col = n * 16 + mrow;
            A[(size_t)node * D + col]  = f2bf(accA[n][reg] + bb[n]);
            Bm[(size_t)node * D + col] = f2bf(accB[n][reg]);
        }
    }
}

// ---------------- E1: uniform edge MLP (wave = 16 CSR-consecutive edges) ----
// No loops, no masking: 800000/16 = 50000 full tiles. Writes ef with
// per-row column permutation p = mrow*8 + n (holds logical col k = n*16+mrow)
// so each lane emits 4 fully-coalesced 16B stores straight from the C-layout.
__global__ __launch_bounds__(256) void edgemlp_kernel(
        const unsigned short* __restrict__ Abf,
        const unsigned short* __restrict__ Bbf,
        const int* __restrict__ erow,
        const int* __restrict__ ecol,
        const float* __restrict__ ed2,
        const unsigned short* __restrict__ wlf,
        const unsigned short* __restrict__ W2f,
        const float* __restrict__ b2e,
        unsigned short* __restrict__ ef) {
    const int t    = threadIdx.x;
    const int wv   = t >> 6;
    const int lane = t & 63;
    const int mrow = lane & 15;
    const int quad = lane >> 4;
    const int tile = blockIdx.x * 4 + wv;       // 12500 * 4 = 50000 exact
    const int e0   = tile * 16;
    const int eme  = e0 + mrow;                 // this lane's A-frag edge

    const int   r  = erow[eme];                 // CSR-sorted -> L1 broadcast
    const int   c  = ecol[eme];
    const float d2 = ed2[eme];

    const uint4* arow = (const uint4*)(Abf + ((size_t)r << 7));
    const uint4* brow = (const uint4*)(Bbf + ((size_t)c << 7));
    const uint4* wlq  = (const uint4*)wlf;
    const uint4* w2p  = (const uint4*)W2f;

    floatx4 acc[8];
    #pragma unroll
    for (int k = 0; k < 8; ++k) acc[k] = (floatx4){0.f, 0.f, 0.f, 0.f};

    #pragma unroll
    for (int s = 0; s < 4; ++s) {
        uint4 au = arow[s * 4 + quad];
        uint4 bu = brow[s * 4 + quad];
        uint4 wu = wlq[s * 4 + quad];

        float a0, a1, a2, a3, a4, a5, a6, a7;
        float q0, q1, q2, q3, q4, q5, q6, q7;
        float w0, w1, w2, w3, w4, w5, w6, w7;
        unpk(au.x, a0, a1); unpk(au.y, a2, a3);
        unpk(au.z, a4, a5); unpk(au.w, a6, a7);
        unpk(bu.x, q0, q1); unpk(bu.y, q2, q3);
        unpk(bu.z, q4, q5); unpk(bu.w, q6, q7);
        unpk(wu.x, w0, w1); unpk(wu.y, w2, w3);
        unpk(wu.z, w4, w5); unpk(wu.w, w6, w7);

        float h0 = silu_f(fmaf(d2, w0, a0 + q0));
        float h1 = silu_f(fmaf(d2, w1, a1 + q1));
        float h2 = silu_f(fmaf(d2, w2, a2 + q2));
        float h3 = silu_f(fmaf(d2, w3, a3 + q3));
        float h4 = silu_f(fmaf(d2, w4, a4 + q4));
        float h5 = silu_f(fmaf(d2, w5, a5 + q5));
        float h6 = silu_f(fmaf(d2, w6, a6 + q6));
        float h7 = silu_f(fmaf(d2, w7, a7 + q7));

        union { shortx8 v; __hip_bfloat162 p[4]; } af;
        af.p[0] = __float22bfloat162_rn(float2{h0, h1});
        af.p[1] = __float22bfloat162_rn(float2{h2, h3});
        af.p[2] = __float22bfloat162_rn(float2{h4, h5});
        af.p[3] = __float22bfloat162_rn(float2{h6, h7});

        const int base = (s * 4 + quad) * 128 + mrow;
        #pragma unroll
        for (int k = 0; k < 8; ++k) {
            union { uint4 u; shortx8 v; } bf;
            bf.u = w2p[base + k * 16];
            acc[k] = __builtin_amdgcn_mfma_f32_16x16x32_bf16(af.v, bf.v, acc[k], 0, 0, 0);
        }
    }

    float bias[8];
    #pragma unroll
    for (int k = 0; k < 8; ++k) bias[k] = b2e[k * 16 + mrow];

    #pragma unroll
    for (int reg = 0; reg < 4; ++reg) {
        const int edge = e0 + quad * 4 + reg;   // C-layout row = edge-in-tile
        union { uint4 u; __hip_bfloat162 p[4]; } ov;
        #pragma unroll
        for (int n = 0; n < 4; ++n) {
            float v0 = silu_f(acc[2 * n + 0][reg] + bias[2 * n + 0]);
            float v1 = silu_f(acc[2 * n + 1][reg] + bias[2 * n + 1]);
            ov.p[n] = __float22bfloat162_rn(float2{v0, v1});
        }
        *(uint4*)(ef + (((size_t)edge) << 7) + mrow * 8) = ov.u;
    }
}

// ---------------- E2: segmented sum over CSR ef rows (wave = node) ----------
// 16B/lane loads: one wave-load covers 4 rows (1024B contiguous). Sums
// reduced across the 4 sub-groups; lanes 0-15 write the canonical f32 row.
__global__ __launch_bounds__(256) void aggsum_kernel(
        const unsigned short* __restrict__ ef,
        const int* __restrict__ rowptr,
        float* __restrict__ aggf) {
    const int t    = threadIdx.x;
    const int lane = t & 63;
    const int node = blockIdx.x * 4 + (t >> 6);  // 12500 * 4 = 50000 exact
    const int start = rowptr[node];
    const int end   = rowptr[node + 1];
    const int sub  = lane >> 4;                  // row within 4-row block
    const int j    = lane & 15;                  // 16B chunk within row

    const uint4* ef4 = (const uint4*)ef;         // row = 16 uint4

    float s[8];
    #pragma unroll
    for (int i = 0; i < 8; ++i) s[i] = 0.f;

    for (int e = start; e < end; e += 4) {
        const int  er    = e + sub;
        const bool valid = er < end;
        const int  safe  = valid ? er : start;
        uint4 u = ef4[(size_t)safe * 16 + j];
        float f0, f1, f2, f3, f4, f5, f6, f7;
        unpk(u.x, f0, f1); unpk(u.y, f2, f3);
        unpk(u.z, f4, f5); unpk(u.w, f6, f7);
        if (valid) {
            s[0] += f0; s[1] += f1; s[2] += f2; s[3] += f3;
            s[4] += f4; s[5] += f5; s[6] += f6; s[7] += f7;
        }
    }
    #pragma unroll
    for (int i = 0; i < 8; ++i) {
        s[i] += __shfl_xor(s[i], 16);
        s[i] += __shfl_xor(s[i], 32);
    }
    if (sub == 0) {
        // permuted position p = j*8 + i  ->  canonical col k = i*16 + j
        float* dst = aggf + ((size_t)node << 7) + j;
        #pragma unroll
        for (int i = 0; i < 8; ++i) dst[i * 16] = s[i];
    }
}

// ---------------- fallback: fused edge MLP + aggregation (f32 agg out) -----
__global__ __launch_bounds__(256, 2) void edgeagg_kernel(
        const unsigned short* __restrict__ Abf,
        const unsigned short* __restrict__ Bbf,
        const int* __restrict__ rowptr,
        const int* __restrict__ ecol,
        const float* __restrict__ ed2,
        const unsigned short* __restrict__ wlf,
        const unsigned short* __restrict__ W2f,
        const float* __restrict__ b2e,
        float* __restrict__ aggf) {
    const int t    = threadIdx.x;
    const int wv   = t >> 6;
    const int lane = t & 63;
    const int mrow = lane & 15;
    const int quad = lane >> 4;
    const int node = blockIdx.x * 4 + wv;        // 12500 * 4 = 50000 exact

    const int start = rowptr[node];
    const int d     = rowptr[node + 1] - start;

    const uint4* arow = (const uint4*)(Abf + ((size_t)node << 7));
    const uint4* wlq  = (const uint4*)wlf;
    uint4 au[4], wlu[4];
    #pragma unroll
    for (int s = 0; s < 4; ++s) {
        au[s]  = arow[s * 4 + quad];
        wlu[s] = wlq[s * 4 + quad];
    }
    float bias[8];
    #pragma unroll
    for (int k = 0; k < 8; ++k) bias[k] = b2e[k * 16 + mrow];

    float nacc[8];
    #pragma unroll
    for (int k = 0; k < 8; ++k) nacc[k] = 0.f;

    const uint4* w2p = (const uint4*)W2f;

    for (int tb = 0; tb < d; tb += 16) {
        const int  ei16 = tb + mrow;
        const bool ve   = ei16 < d;
        const int  idx  = start + (ve ? ei16 : 0);
        const int  c    = ecol[idx];
        float d2        = ed2[idx];
        d2 = ve ? d2 : 0.f;
        const uint4* brow = (const uint4*)(Bbf + ((size_t)c << 7));

        floatx4 acc[8];
        #pragma unroll
        for (int k = 0; k < 8; ++k) acc[k] = (floatx4){0.f, 0.f, 0.f, 0.f};

        #pragma unroll
        for (int s = 0; s < 4; ++s) {
            uint4 bu = brow[s * 4 + quad];

            float a0, a1, a2, a3, a4, a5, a6, a7;
            float q0, q1, q2, q3, q4, q5, q6, q7;
            float w0, w1, w2, w3, w4, w5, w6, w7;
            unpk(au[s].x, a0, a1); unpk(au[s].y, a2, a3);
            unpk(au[s].z, a4, a5); unpk(au[s].w, a6, a7);
            unpk(bu.x, q0, q1); unpk(bu.y, q2, q3);
            unpk(bu.z, q4, q5); unpk(bu.w, q6, q7);
            unpk(wlu[s].x, w0, w1); unpk(wlu[s].y, w2, w3);
            unpk(wlu[s].z, w4, w5); unpk(wlu[s].w, w6, w7);

            float h0 = silu_f(fmaf(d2, w0, a0 + q0));
            float h1 = silu_f(fmaf(d2, w1, a1 + q1));
            float h2 = silu_f(fmaf(d2, w2, a2 + q2));
            float h3 = silu_f(fmaf(d2, w3, a3 + q3));
            float h4 = silu_f(fmaf(d2, w4, a4 + q4));
            float h5 = silu_f(fmaf(d2, w5, a5 + q5));
            float h6 = silu_f(fmaf(d2, w6, a6 + q6));
            float h7 = silu_f(fmaf(d2, w7, a7 + q7));

            union { shortx8 v; __hip_bfloat162 p[4]; } af;
            af.p[0] = __float22bfloat162_rn(float2{h0, h1});
            af.p[1] = __float22bfloat162_rn(float2{h2, h3});
            af.p[2] = __float22bfloat162_rn(float2{h4, h5});
            af.p[3] = __float22bfloat162_rn(float2{h6, h7});

            const int base = (s * 4 + quad) * 128 + mrow;
            #pragma unroll
            for (int k = 0; k < 8; ++k) {
                union { uint4 u; shortx8 v; } bf;
                bf.u = w2p[base + k * 16];
                acc[k] = __builtin_amdgcn_mfma_f32_16x16x32_bf16(af.v, bf.v, acc[k], 0, 0, 0);
            }
        }

        #pragma unroll
        for (int reg = 0; reg < 4; ++reg) {
            const bool vr = (tb + quad * 4 + reg) < d;
            #pragma unroll
            for (int k = 0; k < 8; ++k)
                nacc[k] += vr ? silu_f(acc[k][reg] + bias[k]) : 0.f;
        }
    }

    #pragma unroll
    for (int k = 0; k < 8; ++k) {
        float v = nacc[k];
        v += __shfl_xor(v, 16);
        v += __shfl_xor(v, 32);
        nacc[k] = v;
    }
    const int n8a = quad * 2, n8b = quad * 2 + 1;
    aggf[(size_t)node * D + n8a * 16 + mrow] = nacc[n8a];
    aggf[(size_t)node * D + n8b * 16 + mrow] = nacc[n8b];
}

// ---------------- node MLP + residual + LayerNorm  [MFMA] ----------------
// 1 wave per block, block = 16 nodes. Stage1 K=256 ([x|agg] bf16), transpose
// via LDS (304 B pitch), stage2 K=128, epilogue residual + LN via quad shfl.
// agg arrives as f32; packed to bf16 frags on load.
__global__ __launch_bounds__(64) void node_kernel(
        const unsigned short* __restrict__ xbf,
        const float* __restrict__ aggf,
        const unsigned short* __restrict__ w1nf,  // 256x128 swizzled
        const float* __restrict__ b1n,
        const unsigned short* __restrict__ w2nf,  // 128x128 swizzled
        const float* __restrict__ b2n,
        const float* __restrict__ x,
        const float* __restrict__ gamma,
        const float* __restrict__ beta,
        float* __restrict__ out) {
    __shared__ __align__(16) unsigned short ts[16 * TPITCH];
    const int lane = threadIdx.x;
    const int mrow = lane & 15;
    const int quad = lane >> 4;
    const int n0 = blockIdx.x * 16;      // 3125 blocks exact

    const uint4*  xrow  = (const uint4*)(xbf + ((size_t)(n0 + mrow) << 7));
    const float4* growf = (const float4*)(aggf + ((size_t)(n0 + mrow) << 7));
    const uint4*  w1p   = (const uint4*)w1nf;
    const uint4*  w2p   = (const uint4*)w2nf;

    floatx4 acc[8];
    #pragma unroll
    for (int n = 0; n < 8; ++n) {
        float b = b1n[n * 16 + mrow];
        acc[n] = (floatx4){b, b, b, b};
    }

    #pragma unroll
    for (int s = 0; s < 4; ++s) {
        union { uint4 u; shortx8 v; } af;
        af.u = xrow[s * 4 + quad];
        const int base = (s * 4 + quad) * 128 + mrow;
        #pragma unroll
        for (int n = 0; n < 8; ++n) {
            union { uint4 u; shortx8 v; } bf;
            bf.u = w1p[base + n * 16];
            acc[n] = __builtin_amdgcn_mfma_f32_16x16x32_bf16(af.v, bf.v, acc[n], 0, 0, 0);
        }
    }
    #pragma unroll
    for (int s = 0; s < 4; ++s) {
        float4 g0 = growf[(s * 4 + quad) * 2 + 0];
        float4 g1 = growf[(s * 4 + quad) * 2 + 1];
        union { shortx8 v; __hip_bfloat162 p[4]; } af;
        af.p[0] = __float22bfloat162_rn(float2{g0.x, g0.y});
        af.p[1] = __float22bfloat162_rn(float2{g0.z, g0.w});
        af.p[2] = __float22bfloat162_rn(float2{g1.x, g1.y});
        af.p[3] = __float22bfloat162_rn(float2{g1.z, g1.w});
        const int base = ((s + 4) * 4 + quad) * 128 + mrow;
        #pragma unroll
        for (int n = 0; n < 8; ++n) {
            union { uint4 u; shortx8 v; } bf;
            bf.u = w1p[base + n * 16];
            acc[n] = __builtin_amdgcn_mfma_f32_16x16x32_bf16(af.v, bf.v, acc[n], 0, 0, 0);
        }
    }

    // silu -> LDS (row-major [m][col], transpose for stage-2 A-frags)
    #pragma unroll
    for (int reg = 0; reg < 4; ++reg) {
        const int m = quad * 4 + reg;
        #pragma unroll
        for (int n = 0; n < 8; ++n)
            ts[m * TPITCH + n * 16 + mrow] = f2bf(silu_f(acc[n][reg]));
    }
    __syncthreads();   // single wave: cheap; guarantees LDS RAW ordering

    floatx4 acc2[8];
    #pragma unroll
    for (int n = 0; n < 8; ++n) {
        float b = b2n[n * 16 + mrow];
        acc2[n] = (floatx4){b, b, b, b};
    }
    #pragma unroll
    for (int s = 0; s < 4; ++s) {
        shortx8 af2 = *(const shortx8*)((const char*)ts +
                        mrow * (TPITCH * 2) + (s * 4 + quad) * 16);
        const int base = (s * 4 + quad) * 128 + mrow;
        #pragma unroll
        for (int n = 0; n < 8; ++n) {
            union { uint4 u; shortx8 v; } bf;
            bf.u = w2p[base + n * 16];
            acc2[n] = __builtin_amdgcn_mfma_f32_16x16x32_bf16(af2, bf.v, acc2[n], 0, 0, 0);
        }
    }

    // epilogue: residual + LayerNorm (reduce over the 16 lanes of each quad)
    float g[8], bt[8];
    #pragma unroll
    for (int n = 0; n < 8; ++n) {
        g[n]  = gamma[n * 16 + mrow];
        bt[n] = beta[n * 16 + mrow];
    }
    #pragma unroll
    for (int reg = 0; reg < 4; ++reg) {
        const int node = n0 + quad * 4 + reg;
        float u[8];
        float s1 = 0.f, s2 = 0.f;
        #pragma unroll
        for (int n = 0; n < 8; ++n) {
            u[n] = acc2[n][reg] + x[(size_t)node * D + n * 16 + mrow];
            s1 += u[n];
            s2 += u[n] * u[n];
        }
        #pragma unroll
        for (int off = 1; off < 16; off <<= 1) {
            s1 += __shfl_xor(s1, off);
            s2 += __shfl_xor(s2, off);
        }
        const float mu  = s1 * (1.f / 128.f);
        const float var = s2 * (1.f / 128.f) - mu * mu;
        const float rs  = rsqrtf(var + 1e-5f);
        #pragma unroll
        for (int n = 0; n < 8; ++n)
            out[(size_t)node * D + n * 16 + mrow] = (u[n] - mu) * rs * g[n] + bt[n];
    }
}

extern "C" void kernel_launch(void* const* d_in, const int* in_sizes, int n_in,
                              void* d_out, int out_size, void* d_ws, size_t ws_size,
                              hipStream_t stream) {
    const float* x     = (const float*)d_in[0];
    const float* pos   = (const float*)d_in[1];
    const int*   ei    = (const int*)d_in[2];
    const float* W1e   = (const float*)d_in[3];
    const float* b1e   = (const float*)d_in[4];
    const float* W2e   = (const float*)d_in[5];
    const float* b2e   = (const float*)d_in[6];
    const float* W1n   = (const float*)d_in[7];
    const float* b1n   = (const float*)d_in[8];
    const float* W2n   = (const float*)d_in[9];
    const float* b2n   = (const float*)d_in[10];
    const float* gamma = (const float*)d_in[11];
    const float* beta  = (const float*)d_in[12];
    float* out = (float*)d_out;

    // ws layout (all heavy-read buffers 16B-aligned).
    // Key lifetime fact: Abf/Bbf are dead after edgemlp; aggf (25.6 MB f32)
    // exactly aliases Abf+Bbf (2*12.8 MB) in the bigws path, keeping total
    // footprint ~253.8 MB < 256 MiB. In the fallback path aggf lives where
    // ef would have gone (ef unused there), so it never aliases live data.
    int*            deg    = (int*)d_ws;                              // 50176
    int*            part   = deg + 50176;
    int*            bsum   = part + 50176;
    int*            boff   = bsum + 256;
    int*            rowptr = boff + 256;                              // 50004
    int*            cursor = rowptr + 50004;                          // 50000
    int*            ecol   = cursor + 50000;                          // 800000
    int*            erow   = ecol + NE;                               // 800000
    float*          ed2    = (float*)(erow + NE);                     // 800000
    unsigned short* Abf    = (unsigned short*)(ed2 + NE);             // 12.8 MB
    unsigned short* Bbf    = Abf + (size_t)NND * D;                   // 12.8 MB
    unsigned short* xbf    = Bbf + (size_t)NND * D;                   // 12.8 MB
    unsigned short* w1f    = xbf + (size_t)NND * D;                   // 64 KB (256x128)
    unsigned short* w1nf   = w1f + 256 * D;                           // 64 KB (256x128)
    unsigned short* w2f    = w1nf + 256 * D;                          // 32 KB (128x128)
    unsigned short* w2nf   = w2f + D * D;                             // 32 KB (128x128)
    unsigned short* wlf    = w2nf + D * D;                            // 256 B
    unsigned short* ef     = wlf + 128;                               // 204.8 MB (bf16 edge feats)

    const size_t need_big = (size_t)((char*)(ef + (size_t)NE * D) - (char*)d_ws);
    const bool bigws = ws_size >= need_big;

    // aggf: alias dead Abf/Bbf (bigws) or the unused ef slot (fallback)
    float* aggf = bigws ? (float*)Abf : (float*)ef;

    // zero deg only (aggf fully overwritten by aggsum/edgeagg; ef by edgemlp)
    zero_kernel<<<49, 256, 0, stream>>>((float4*)deg, 50176 / 4);

    // CSR build
    hist_kernel<<<NE / 256, 256, 0, stream>>>(ei, deg);
    scan1_kernel<<<NB1, 256, 0, stream>>>(deg, part, bsum);
    scan2_kernel<<<1, 256, 0, stream>>>(bsum, boff);
    scan3_kernel<<<197, 256, 0, stream>>>(part, boff, rowptr, cursor);
    scatter_kernel<<<NE / 256, 256, 0, stream>>>(ei, pos, cursor, ecol, erow, ed2);

    // fused weight swizzles (1 launch) + x conversion
    wswzall_kernel<<<385, 256, 0, stream>>>(W1e, W1n, W2e, W2n,
                                            w1f, w1nf, w2f, w2nf, wlf);
    x2bf_kernel<<<(NND * D / 4) / 256, 256, 0, stream>>>((const float4*)x, (uint2*)xbf);

    // A'/B precompute (MFMA)
    precompute_kernel<<<782, 256, 0, stream>>>(xbf, w1f, b1e, Abf, Bbf);

    if (bigws) {
        // E1: uniform edge MLP -> ef (CSR order, col-permuted rows)
        edgemlp_kernel<<<NE / 16 / 4, 256, 0, stream>>>(Abf, Bbf, erow, ecol, ed2,
                                                        wlf, w2f, b2e, ef);
        // E2: segmented sum -> aggf (canonical f32 layout; aggf aliases
        // Abf/Bbf, both dead after edgemlp)
        aggsum_kernel<<<NND / 4, 256, 0, stream>>>(ef, rowptr, aggf);
    } else {
        // fallback: fused per-node path (workspace too small for ef)
        edgeagg_kernel<<<NND / 4, 256, 0, stream>>>(Abf, Bbf, rowptr, ecol, ed2,
                                                    wlf, w2f, b2e, aggf);
    }

    // node MLP + residual + LN (MFMA)
    node_kernel<<<NND / 16, 64, 0, stream>>>(xbf, aggf, w1nf, b1n, w2nf, b2n,
                                             x, gamma, beta, out);
}

// Round 5
// 379.115 us; speedup vs baseline: 1.3620x; 1.0962x over previous
//
#include <hip/hip_runtime.h>
#include <hip/hip_bf16.h>
#include <math.h>

#define D 128
#define NND 50000
#define NE 800000
#define NB1 196        // scan blocks: 196*256 = 50176 >= 50000
#define TPITCH 152     // ushort pitch for node transpose tile (304 B = 19*16)

typedef __attribute__((ext_vector_type(8))) short shortx8;
typedef __attribute__((ext_vector_type(4))) float floatx4;

__device__ __forceinline__ float silu_f(float v) {
    // v / (1+e^-v) with hardware rcp (1 ulp) instead of IEEE divide
    return v * __builtin_amdgcn_rcpf(1.0f + __expf(-v));
}
__device__ __forceinline__ unsigned short f2bf(float f) {
    union { float f; unsigned int u; } v; v.f = f;
    unsigned int u = v.u;
    u += 0x7fffu + ((u >> 16) & 1u);   // RNE
    return (unsigned short)(u >> 16);
}
__device__ __forceinline__ void unpk(unsigned int u, float& lo, float& hi) {
    union { unsigned int x; float f; } a, b;
    a.x = u << 16;
    b.x = u & 0xffff0000u;
    lo = a.f; hi = b.f;
}

// ---------------- zero (deg) ----------------
__global__ void zero_kernel(float4* __restrict__ p, int n4) {
    int i = blockIdx.x * blockDim.x + threadIdx.x;
    float4 z = make_float4(0.f, 0.f, 0.f, 0.f);
    for (; i < n4; i += gridDim.x * blockDim.x) p[i] = z;
}

// ---------------- CSR build ----------------
__global__ void hist_kernel(const int* __restrict__ ei, int* __restrict__ deg) {
    int e = blockIdx.x * 256 + threadIdx.x;     // NE = 3125*256 exactly
    atomicAdd(&deg[ei[e]], 1);
}

__global__ void scan1_kernel(const int* __restrict__ deg,
                             int* __restrict__ part, int* __restrict__ bsum) {
    __shared__ int s[256];
    const int tid = threadIdx.x;
    const int i = blockIdx.x * 256 + tid;
    int v = (i < NND) ? deg[i] : 0;
    s[tid] = v;
    __syncthreads();
    #pragma unroll
    for (int off = 1; off < 256; off <<= 1) {
        int t = (tid >= off) ? s[tid - off] : 0;
        __syncthreads();
        s[tid] += t;
        __syncthreads();
    }
    part[i] = s[tid] - v;                        // exclusive
    if (tid == 255) bsum[blockIdx.x] = s[255];
}

__global__ void scan2_kernel(const int* __restrict__ bsum, int* __restrict__ boff) {
    __shared__ int s[256];
    const int tid = threadIdx.x;
    int v = (tid < NB1) ? bsum[tid] : 0;
    s[tid] = v;
    __syncthreads();
    #pragma unroll
    for (int off = 1; off < 256; off <<= 1) {
        int t = (tid >= off) ? s[tid - off] : 0;
        __syncthreads();
        s[tid] += t;
        __syncthreads();
    }
    if (tid < NB1) boff[tid] = s[tid] - v;       // exclusive
}

__global__ void scan3_kernel(const int* __restrict__ part, const int* __restrict__ boff,
                             int* __restrict__ rowptr, int* __restrict__ cursor) {
    int i = blockIdx.x * 256 + threadIdx.x;
    if (i < NND) {
        int v = part[i] + boff[i >> 8];
        rowptr[i] = v;
        cursor[i] = v;
    } else if (i == NND) {
        rowptr[NND] = NE;
    }
}

// scatter packed {col, row, dist2} into CSR order: ONE 16B store per edge
__global__ void scatter_kernel(const int* __restrict__ ei, const float* __restrict__ pos,
                               int* __restrict__ cursor,
                               uint4* __restrict__ epack) {
    int e = blockIdx.x * 256 + threadIdx.x;     // NE exact multiple of 256
    int r = ei[e], c = ei[NE + e];
    float dx = pos[r * 3 + 0] - pos[c * 3 + 0];
    float dy = pos[r * 3 + 1] - pos[c * 3 + 1];
    float dz = pos[r * 3 + 2] - pos[c * 3 + 2];
    float d2 = dx * dx + dy * dy + dz * dz;
    int slot = atomicAdd(&cursor[r], 1);
    uint4 v;
    v.x = (unsigned int)c;
    v.y = (unsigned int)r;
    v.z = __float_as_uint(d2);
    v.w = 0u;
    epack[slot] = v;
}

// ---------------- fused weight swizzle (all 4 matrices + wlf, 1 launch) ----
// Wf flat f = (((ks*4+quad)*128)+n*16+mrow)*8+j  <->  W[k=ks*32+quad*8+j][col=n*16+mrow]
__global__ void wswzall_kernel(const float* __restrict__ W1e, const float* __restrict__ W1n,
                               const float* __restrict__ W2e, const float* __restrict__ W2n,
                               unsigned short* __restrict__ w1f, unsigned short* __restrict__ w1nf,
                               unsigned short* __restrict__ w2f, unsigned short* __restrict__ w2nf,
                               unsigned short* __restrict__ wlf) {
    const int b = blockIdx.x;
    const float* W; unsigned short* Wf; int lb;
    if (b < 128)      { W = W1e; Wf = w1f;  lb = b; }
    else if (b < 256) { W = W1n; Wf = w1nf; lb = b - 128; }
    else if (b < 320) { W = W2e; Wf = w2f;  lb = b - 256; }
    else if (b < 384) { W = W2n; Wf = w2nf; lb = b - 320; }
    else {
        if (threadIdx.x < 128) wlf[threadIdx.x] = f2bf(W1e[256 * D + threadIdx.x]);
        return;
    }
    int f = lb * 256 + threadIdx.x;
    int j    = f & 7;
    int mrow = (f >> 3) & 15;
    int n    = (f >> 7) & 7;
    int rest = f >> 10;
    int quad = rest & 3;
    int ks   = rest >> 2;
    int col = n * 16 + mrow;
    int k   = ks * 32 + quad * 8 + j;
    Wf[f] = f2bf(W[k * D + col]);
}

// ---------------- A' = bf16(x@W1e_top + b1e), B = bf16(x@W1e_bot)  [MFMA] ----
// reads x f32 directly, converts A-frags inline (no separate xbf pass)
__global__ __launch_bounds__(256) void precompute_kernel(
        const float* __restrict__ x,
        const unsigned short* __restrict__ w1f,   // 256x128 swizzled
        const float* __restrict__ b1e,
        unsigned short* __restrict__ A,
        unsigned short* __restrict__ Bm) {
    const int t    = threadIdx.x;
    const int wv   = t >> 6;
    const int lane = t & 63;
    const int mrow = lane & 15;
    const int quad = lane >> 4;
    const int tile = blockIdx.x * 4 + wv;
    if (tile >= 3125) return;
    const int n0 = tile * 16;

    const float4* xrow = (const float4*)(x + ((size_t)(n0 + mrow) << 7));
    const uint4* wp   = (const uint4*)w1f;

    floatx4 accA[8], accB[8];
    #pragma unroll
    for (int n = 0; n < 8; ++n) {
        accA[n] = (floatx4){0.f, 0.f, 0.f, 0.f};
        accB[n] = (floatx4){0.f, 0.f, 0.f, 0.f};
    }

    #pragma unroll
    for (int s = 0; s < 4; ++s) {
        float4 xa = xrow[(s * 4 + quad) * 2 + 0];
        float4 xb = xrow[(s * 4 + quad) * 2 + 1];
        union { shortx8 v; __hip_bfloat162 p[4]; } af;
        af.p[0] = __float22bfloat162_rn(float2{xa.x, xa.y});
        af.p[1] = __float22bfloat162_rn(float2{xa.z, xa.w});
        af.p[2] = __float22bfloat162_rn(float2{xb.x, xb.y});
        af.p[3] = __float22bfloat162_rn(float2{xb.z, xb.w});
        const int baseA = (s * 4 + quad) * 128 + mrow;
        const int baseB = ((s + 4) * 4 + quad) * 128 + mrow;
        #pragma unroll
        for (int n = 0; n < 8; ++n) {
            union { uint4 u; shortx8 v; } bfA, bfB;
            bfA.u = wp[baseA + n * 16];
            bfB.u = wp[baseB + n * 16];
            accA[n] = __builtin_amdgcn_mfma_f32_16x16x32_bf16(af.v, bfA.v, accA[n], 0, 0, 0);
            accB[n] = __builtin_amdgcn_mfma_f32_16x16x32_bf16(af.v, bfB.v, accB[n], 0, 0, 0);
        }
    }

    float bb[8];
    #pragma unroll
    for (int n = 0; n < 8; ++n) bb[n] = b1e[n * 16 + mrow];

    #pragma unroll
    for (int reg = 0; reg < 4; ++reg) {
        const int node = n0 + quad * 4 + reg;
        #pragma unroll
        for (int n = 0; n < 8; ++n) {
            const int col = n * 16 + mrow;
            A[(size_t)node * D + col]  = f2bf(accA[n][reg] + bb[n]);
            Bm[(size_t)node * D + col] = f2bf(accB[n][reg]);
        }
    }
}

// ---------------- E1: uniform edge MLP (wave = 16 CSR-consecutive edges) ----
// No loops, no masking: 800000/16 = 50000 full tiles. Writes ef with
// per-row column permutation p = mrow*8 + n (holds logical col k = n*16+mrow)
// so each lane emits 4 fully-coalesced 16B stores straight from the C-layout.
__global__ __launch_bounds__(256, 2) void edgemlp_kernel(
        const unsigned short* __restrict__ Abf,
        const unsigned short* __restrict__ Bbf,
        const uint4* __restrict__ epack,
        const unsigned short* __restrict__ wlf,
        const unsigned short* __restrict__ W2f,
        const float* __restrict__ b2e,
        unsigned short* __restrict__ ef) {
    const int t    = threadIdx.x;
    const int wv   = t >> 6;
    const int lane = t & 63;
    const int mrow = lane & 15;
    const int quad = lane >> 4;
    const int tile = blockIdx.x * 4 + wv;       // 12500 * 4 = 50000 exact
    const int e0   = tile * 16;
    const int eme  = e0 + mrow;                 // this lane's A-frag edge

    const uint4 ep = epack[eme];                // single coalesced 16B gather
    const int   c  = (int)ep.x;
    const int   r  = (int)ep.y;                 // CSR-sorted -> L1 broadcast
    const float d2 = __uint_as_float(ep.z);

    const uint4* arow = (const uint4*)(Abf + ((size_t)r << 7));
    const uint4* brow = (const uint4*)(Bbf + ((size_t)c << 7));
    const uint4* wlq  = (const uint4*)wlf;
    const uint4* w2p  = (const uint4*)W2f;

    floatx4 acc[8];
    #pragma unroll
    for (int k = 0; k < 8; ++k) acc[k] = (floatx4){0.f, 0.f, 0.f, 0.f};

    #pragma unroll
    for (int s = 0; s < 4; ++s) {
        uint4 au = arow[s * 4 + quad];
        uint4 bu = brow[s * 4 + quad];
        uint4 wu = wlq[s * 4 + quad];

        float a0, a1, a2, a3, a4, a5, a6, a7;
        float q0, q1, q2, q3, q4, q5, q6, q7;
        float w0, w1, w2, w3, w4, w5, w6, w7;
        unpk(au.x, a0, a1); unpk(au.y, a2, a3);
        unpk(au.z, a4, a5); unpk(au.w, a6, a7);
        unpk(bu.x, q0, q1); unpk(bu.y, q2, q3);
        unpk(bu.z, q4, q5); unpk(bu.w, q6, q7);
        unpk(wu.x, w0, w1); unpk(wu.y, w2, w3);
        unpk(wu.z, w4, w5); unpk(wu.w, w6, w7);

        float h0 = silu_f(fmaf(d2, w0, a0 + q0));
        float h1 = silu_f(fmaf(d2, w1, a1 + q1));
        float h2 = silu_f(fmaf(d2, w2, a2 + q2));
        float h3 = silu_f(fmaf(d2, w3, a3 + q3));
        float h4 = silu_f(fmaf(d2, w4, a4 + q4));
        float h5 = silu_f(fmaf(d2, w5, a5 + q5));
        float h6 = silu_f(fmaf(d2, w6, a6 + q6));
        float h7 = silu_f(fmaf(d2, w7, a7 + q7));

        union { shortx8 v; __hip_bfloat162 p[4]; } af;
        af.p[0] = __float22bfloat162_rn(float2{h0, h1});
        af.p[1] = __float22bfloat162_rn(float2{h2, h3});
        af.p[2] = __float22bfloat162_rn(float2{h4, h5});
        af.p[3] = __float22bfloat162_rn(float2{h6, h7});

        const int base = (s * 4 + quad) * 128 + mrow;
        #pragma unroll
        for (int k = 0; k < 8; ++k) {
            union { uint4 u; shortx8 v; } bf;
            bf.u = w2p[base + k * 16];
            acc[k] = __builtin_amdgcn_mfma_f32_16x16x32_bf16(af.v, bf.v, acc[k], 0, 0, 0);
        }
    }

    float bias[8];
    #pragma unroll
    for (int k = 0; k < 8; ++k) bias[k] = b2e[k * 16 + mrow];

    #pragma unroll
    for (int reg = 0; reg < 4; ++reg) {
        const int edge = e0 + quad * 4 + reg;   // C-layout row = edge-in-tile
        union { uint4 u; __hip_bfloat162 p[4]; } ov;
        #pragma unroll
        for (int n = 0; n < 4; ++n) {
            float v0 = silu_f(acc[2 * n + 0][reg] + bias[2 * n + 0]);
            float v1 = silu_f(acc[2 * n + 1][reg] + bias[2 * n + 1]);
            ov.p[n] = __float22bfloat162_rn(float2{v0, v1});
        }
        *(uint4*)(ef + (((size_t)edge) << 7) + mrow * 8) = ov.u;
    }
}

// ---------------- E2: segmented sum over CSR ef rows (wave = node) ----------
// 16B/lane loads: one wave-load covers 4 rows (1024B contiguous). Sums
// reduced across the 4 sub-groups; lanes 0-15 write the canonical f32 row.
__global__ __launch_bounds__(256) void aggsum_kernel(
        const unsigned short* __restrict__ ef,
        const int* __restrict__ rowptr,
        float* __restrict__ aggf) {
    const int t    = threadIdx.x;
    const int lane = t & 63;
    const int node = blockIdx.x * 4 + (t >> 6);  // 12500 * 4 = 50000 exact
    const int start = rowptr[node];
    const int end   = rowptr[node + 1];
    const int sub  = lane >> 4;                  // row within 4-row block
    const int j    = lane & 15;                  // 16B chunk within row

    const uint4* ef4 = (const uint4*)ef;         // row = 16 uint4

    float s[8];
    #pragma unroll
    for (int i = 0; i < 8; ++i) s[i] = 0.f;

    for (int e = start; e < end; e += 4) {
        const int  er    = e + sub;
        const bool valid = er < end;
        const int  safe  = valid ? er : start;
        uint4 u = ef4[(size_t)safe * 16 + j];
        float f0, f1, f2, f3, f4, f5, f6, f7;
        unpk(u.x, f0, f1); unpk(u.y, f2, f3);
        unpk(u.z, f4, f5); unpk(u.w, f6, f7);
        if (valid) {
            s[0] += f0; s[1] += f1; s[2] += f2; s[3] += f3;
            s[4] += f4; s[5] += f5; s[6] += f6; s[7] += f7;
        }
    }
    #pragma unroll
    for (int i = 0; i < 8; ++i) {
        s[i] += __shfl_xor(s[i], 16);
        s[i] += __shfl_xor(s[i], 32);
    }
    if (sub == 0) {
        // permuted position p = j*8 + i  ->  canonical col k = i*16 + j
        float* dst = aggf + ((size_t)node << 7) + j;
        #pragma unroll
        for (int i = 0; i < 8; ++i) dst[i * 16] = s[i];
    }
}

// ---------------- fallback: fused edge MLP + aggregation (f32 agg out) -----
__global__ __launch_bounds__(256, 2) void edgeagg_kernel(
        const unsigned short* __restrict__ Abf,
        const unsigned short* __restrict__ Bbf,
        const int* __restrict__ rowptr,
        const uint4* __restrict__ epack,
        const unsigned short* __restrict__ wlf,
        const unsigned short* __restrict__ W2f,
        const float* __restrict__ b2e,
        float* __restrict__ aggf) {
    const int t    = threadIdx.x;
    const int wv   = t >> 6;
    const int lane = t & 63;
    const int mrow = lane & 15;
    const int quad = lane >> 4;
    const int node = blockIdx.x * 4 + wv;        // 12500 * 4 = 50000 exact

    const int start = rowptr[node];
    const int d     = rowptr[node + 1] - start;

    const uint4* arow = (const uint4*)(Abf + ((size_t)node << 7));
    const uint4* wlq  = (const uint4*)wlf;
    uint4 au[4], wlu[4];
    #pragma unroll
    for (int s = 0; s < 4; ++s) {
        au[s]  = arow[s * 4 + quad];
        wlu[s] = wlq[s * 4 + quad];
    }
    float bias[8];
    #pragma unroll
    for (int k = 0; k < 8; ++k) bias[k] = b2e[k * 16 + mrow];

    float nacc[8];
    #pragma unroll
    for (int k = 0; k < 8; ++k) nacc[k] = 0.f;

    const uint4* w2p = (const uint4*)W2f;

    for (int tb = 0; tb < d; tb += 16) {
        const int  ei16 = tb + mrow;
        const bool ve   = ei16 < d;
        const int  idx  = start + (ve ? ei16 : 0);
        const uint4 ep  = epack[idx];
        const int  c    = (int)ep.x;
        float d2        = __uint_as_float(ep.z);
        d2 = ve ? d2 : 0.f;
        const uint4* brow = (const uint4*)(Bbf + ((size_t)c << 7));

        floatx4 acc[8];
        #pragma unroll
        for (int k = 0; k < 8; ++k) acc[k] = (floatx4){0.f, 0.f, 0.f, 0.f};

        #pragma unroll
        for (int s = 0; s < 4; ++s) {
            uint4 bu = brow[s * 4 + quad];

            float a0, a1, a2, a3, a4, a5, a6, a7;
            float q0, q1, q2, q3, q4, q5, q6, q7;
            float w0, w1, w2, w3, w4, w5, w6, w7;
            unpk(au[s].x, a0, a1); unpk(au[s].y, a2, a3);
            unpk(au[s].z, a4, a5); unpk(au[s].w, a6, a7);
            unpk(bu.x, q0, q1); unpk(bu.y, q2, q3);
            unpk(bu.z, q4, q5); unpk(bu.w, q6, q7);
            unpk(wlu[s].x, w0, w1); unpk(wlu[s].y, w2, w3);
            unpk(wlu[s].z, w4, w5); unpk(wlu[s].w, w6, w7);

            float h0 = silu_f(fmaf(d2, w0, a0 + q0));
            float h1 = silu_f(fmaf(d2, w1, a1 + q1));
            float h2 = silu_f(fmaf(d2, w2, a2 + q2));
            float h3 = silu_f(fmaf(d2, w3, a3 + q3));
            float h4 = silu_f(fmaf(d2, w4, a4 + q4));
            float h5 = silu_f(fmaf(d2, w5, a5 + q5));
            float h6 = silu_f(fmaf(d2, w6, a6 + q6));
            float h7 = silu_f(fmaf(d2, w7, a7 + q7));

            union { shortx8 v; __hip_bfloat162 p[4]; } af;
            af.p[0] = __float22bfloat162_rn(float2{h0, h1});
            af.p[1] = __float22bfloat162_rn(float2{h2, h3});
            af.p[2] = __float22bfloat162_rn(float2{h4, h5});
            af.p[3] = __float22bfloat162_rn(float2{h6, h7});

            const int base = (s * 4 + quad) * 128 + mrow;
            #pragma unroll
            for (int k = 0; k < 8; ++k) {
                union { uint4 u; shortx8 v; } bf;
                bf.u = w2p[base + k * 16];
                acc[k] = __builtin_amdgcn_mfma_f32_16x16x32_bf16(af.v, bf.v, acc[k], 0, 0, 0);
            }
        }

        #pragma unroll
        for (int reg = 0; reg < 4; ++reg) {
            const bool vr = (tb + quad * 4 + reg) < d;
            #pragma unroll
            for (int k = 0; k < 8; ++k)
                nacc[k] += vr ? silu_f(acc[k][reg] + bias[k]) : 0.f;
        }
    }

    #pragma unroll
    for (int k = 0; k < 8; ++k) {
        float v = nacc[k];
        v += __shfl_xor(v, 16);
        v += __shfl_xor(v, 32);
        nacc[k] = v;
    }
    const int n8a = quad * 2, n8b = quad * 2 + 1;
    aggf[(size_t)node * D + n8a * 16 + mrow] = nacc[n8a];
    aggf[(size_t)node * D + n8b * 16 + mrow] = nacc[n8b];
}

// ---------------- node MLP + residual + LayerNorm  [MFMA] ----------------
// 1 wave per block, block = 16 nodes. Stage1 K=256 ([x|agg] bf16, converted
// inline from f32), transpose via LDS (304 B pitch), stage2 K=128, epilogue
// residual + LN via quad shfl.
__global__ __launch_bounds__(64) void node_kernel(
        const float* __restrict__ aggf,
        const unsigned short* __restrict__ w1nf,  // 256x128 swizzled
        const float* __restrict__ b1n,
        const unsigned short* __restrict__ w2nf,  // 128x128 swizzled
        const float* __restrict__ b2n,
        const float* __restrict__ x,
        const float* __restrict__ gamma,
        const float* __restrict__ beta,
        float* __restrict__ out) {
    __shared__ __align__(16) unsigned short ts[16 * TPITCH];
    const int lane = threadIdx.x;
    const int mrow = lane & 15;
    const int quad = lane >> 4;
    const int n0 = blockIdx.x * 16;      // 3125 blocks exact

    const float4* xrow  = (const float4*)(x + ((size_t)(n0 + mrow) << 7));
    const float4* growf = (const float4*)(aggf + ((size_t)(n0 + mrow) << 7));
    const uint4*  w1p   = (const uint4*)w1nf;
    const uint4*  w2p   = (const uint4*)w2nf;

    floatx4 acc[8];
    #pragma unroll
    for (int n = 0; n < 8; ++n) {
        float b = b1n[n * 16 + mrow];
        acc[n] = (floatx4){b, b, b, b};
    }

    #pragma unroll
    for (int s = 0; s < 4; ++s) {
        float4 xa = xrow[(s * 4 + quad) * 2 + 0];
        float4 xb = xrow[(s * 4 + quad) * 2 + 1];
        union { shortx8 v; __hip_bfloat162 p[4]; } af;
        af.p[0] = __float22bfloat162_rn(float2{xa.x, xa.y});
        af.p[1] = __float22bfloat162_rn(float2{xa.z, xa.w});
        af.p[2] = __float22bfloat162_rn(float2{xb.x, xb.y});
        af.p[3] = __float22bfloat162_rn(float2{xb.z, xb.w});
        const int base = (s * 4 + quad) * 128 + mrow;
        #pragma unroll
        for (int n = 0; n < 8; ++n) {
            union { uint4 u; shortx8 v; } bf;
            bf.u = w1p[base + n * 16];
            acc[n] = __builtin_amdgcn_mfma_f32_16x16x32_bf16(af.v, bf.v, acc[n], 0, 0, 0);
        }
    }
    #pragma unroll
    for (int s = 0; s < 4; ++s) {
        float4 g0 = growf[(s * 4 + quad) * 2 + 0];
        float4 g1 = growf[(s * 4 + quad) * 2 + 1];
        union { shortx8 v; __hip_bfloat162 p[4]; } af;
        af.p[0] = __float22bfloat162_rn(float2{g0.x, g0.y});
        af.p[1] = __float22bfloat162_rn(float2{g0.z, g0.w});
        af.p[2] = __float22bfloat162_rn(float2{g1.x, g1.y});
        af.p[3] = __float22bfloat162_rn(float2{g1.z, g1.w});
        const int base = ((s + 4) * 4 + quad) * 128 + mrow;
        #pragma unroll
        for (int n = 0; n < 8; ++n) {
            union { uint4 u; shortx8 v; } bf;
            bf.u = w1p[base + n * 16];
            acc[n] = __builtin_amdgcn_mfma_f32_16x16x32_bf16(af.v, bf.v, acc[n], 0, 0, 0);
        }
    }

    // silu -> LDS (row-major [m][col], transpose for stage-2 A-frags)
    #pragma unroll
    for (int reg = 0; reg < 4; ++reg) {
        const int m = quad * 4 + reg;
        #pragma unroll
        for (int n = 0; n < 8; ++n)
            ts[m * TPITCH + n * 16 + mrow] = f2bf(silu_f(acc[n][reg]));
    }
    __syncthreads();   // single wave: cheap; guarantees LDS RAW ordering

    floatx4 acc2[8];
    #pragma unroll
    for (int n = 0; n < 8; ++n) {
        float b = b2n[n * 16 + mrow];
        acc2[n] = (floatx4){b, b, b, b};
    }
    #pragma unroll
    for (int s = 0; s < 4; ++s) {
        shortx8 af2 = *(const shortx8*)((const char*)ts +
                        mrow * (TPITCH * 2) + (s * 4 + quad) * 16);
        const int base = (s * 4 + quad) * 128 + mrow;
        #pragma unroll
        for (int n = 0; n < 8; ++n) {
            union { uint4 u; shortx8 v; } bf;
            bf.u = w2p[base + n * 16];
            acc2[n] = __builtin_amdgcn_mfma_f32_16x16x32_bf16(af2, bf.v, acc2[n], 0, 0, 0);
        }
    }

    // epilogue: residual + LayerNorm (reduce over the 16 lanes of each quad)
    float g[8], bt[8];
    #pragma unroll
    for (int n = 0; n < 8; ++n) {
        g[n]  = gamma[n * 16 + mrow];
        bt[n] = beta[n * 16 + mrow];
    }
    #pragma unroll
    for (int reg = 0; reg < 4; ++reg) {
        const int node = n0 + quad * 4 + reg;
        float u[8];
        float s1 = 0.f, s2 = 0.f;
        #pragma unroll
        for (int n = 0; n < 8; ++n) {
            u[n] = acc2[n][reg] + x[(size_t)node * D + n * 16 + mrow];
            s1 += u[n];
            s2 += u[n] * u[n];
        }
        #pragma unroll
        for (int off = 1; off < 16; off <<= 1) {
            s1 += __shfl_xor(s1, off);
            s2 += __shfl_xor(s2, off);
        }
        const float mu  = s1 * (1.f / 128.f);
        const float var = s2 * (1.f / 128.f) - mu * mu;
        const float rs  = rsqrtf(var + 1e-5f);
        #pragma unroll
        for (int n = 0; n < 8; ++n)
            out[(size_t)node * D + n * 16 + mrow] = (u[n] - mu) * rs * g[n] + bt[n];
    }
}

extern "C" void kernel_launch(void* const* d_in, const int* in_sizes, int n_in,
                              void* d_out, int out_size, void* d_ws, size_t ws_size,
                              hipStream_t stream) {
    const float* x     = (const float*)d_in[0];
    const float* pos   = (const float*)d_in[1];
    const int*   ei    = (const int*)d_in[2];
    const float* W1e   = (const float*)d_in[3];
    const float* b1e   = (const float*)d_in[4];
    const float* W2e   = (const float*)d_in[5];
    const float* b2e   = (const float*)d_in[6];
    const float* W1n   = (const float*)d_in[7];
    const float* b1n   = (const float*)d_in[8];
    const float* W2n   = (const float*)d_in[9];
    const float* b2n   = (const float*)d_in[10];
    const float* gamma = (const float*)d_in[11];
    const float* beta  = (const float*)d_in[12];
    float* out = (float*)d_out;

    // ws layout. Lifetimes: Abf/Bbf die after edgemlp; aggf (25.6 MB f32)
    // aliases Abf+Bbf exactly in the bigws path. Footprint ~244 MB < 256 MiB.
    int*            deg    = (int*)d_ws;                              // 50176
    int*            part   = deg + 50176;
    int*            bsum   = part + 50176;
    int*            boff   = bsum + 256;
    int*            rowptr = boff + 256;                              // 50004
    int*            cursor = rowptr + 50004;                          // 50000
    // 200868 ints = 803472 B, divisible by 16 -> epack aligned
    uint4*          epack  = (uint4*)(cursor + 50000);                // 12.8 MB
    unsigned short* Abf    = (unsigned short*)(epack + NE);           // 12.8 MB
    unsigned short* Bbf    = Abf + (size_t)NND * D;                   // 12.8 MB
    unsigned short* w1f    = Bbf + (size_t)NND * D;                   // 64 KB (256x128)
    unsigned short* w1nf   = w1f + 256 * D;                           // 64 KB (256x128)
    unsigned short* w2f    = w1nf + 256 * D;                          // 32 KB (128x128)
    unsigned short* w2nf   = w2f + D * D;                             // 32 KB (128x128)
    unsigned short* wlf    = w2nf + D * D;                            // 256 B
    unsigned short* ef     = wlf + 128;                               // 204.8 MB (bf16 edge feats)

    const size_t need_big = (size_t)((char*)(ef + (size_t)NE * D) - (char*)d_ws);
    const bool bigws = ws_size >= need_big;

    // aggf: alias dead Abf/Bbf (bigws) or the unused ef slot (fallback)
    float* aggf = bigws ? (float*)Abf : (float*)ef;

    // zero deg only
    zero_kernel<<<49, 256, 0, stream>>>((float4*)deg, 50176 / 4);

    // CSR build
    hist_kernel<<<NE / 256, 256, 0, stream>>>(ei, deg);
    scan1_kernel<<<NB1, 256, 0, stream>>>(deg, part, bsum);
    scan2_kernel<<<1, 256, 0, stream>>>(bsum, boff);
    scan3_kernel<<<197, 256, 0, stream>>>(part, boff, rowptr, cursor);
    scatter_kernel<<<NE / 256, 256, 0, stream>>>(ei, pos, cursor, epack);

    // fused weight swizzles (1 launch)
    wswzall_kernel<<<385, 256, 0, stream>>>(W1e, W1n, W2e, W2n,
                                            w1f, w1nf, w2f, w2nf, wlf);

    // A'/B precompute (MFMA, reads x f32 directly)
    precompute_kernel<<<782, 256, 0, stream>>>(x, w1f, b1e, Abf, Bbf);

    if (bigws) {
        // E1: uniform edge MLP -> ef (CSR order, col-permuted rows)
        edgemlp_kernel<<<NE / 16 / 4, 256, 0, stream>>>(Abf, Bbf, epack,
                                                        wlf, w2f, b2e, ef);
        // E2: segmented sum -> aggf (canonical f32 layout; aliases dead Abf/Bbf)
        aggsum_kernel<<<NND / 4, 256, 0, stream>>>(ef, rowptr, aggf);
    } else {
        // fallback: fused per-node path (workspace too small for ef)
        edgeagg_kernel<<<NND / 4, 256, 0, stream>>>(Abf, Bbf, rowptr, epack,
                                                    wlf, w2f, b2e, aggf);
    }

    // node MLP + residual + LN (MFMA)
    node_kernel<<<NND / 16, 64, 0, stream>>>(aggf, w1nf, b1n, w2nf, b2n,
                                             x, gamma, beta, out);
}